// Round 5
// baseline (124.398 us; speedup 1.0000x reference)
//
#include <hip/hip_runtime.h>

#define N_NODES 40000
#define D 128
#define N_EDGES 640000
#define ENDV 0xFFFFFFFFu
#define CNT_BLOCKS 625   // x 256 threads x 4 edges = 640000
#define GEMM_BLOCKS 1250 // x 32 nodes = 40000

static __device__ __forceinline__ unsigned short f2bf(float f) {
  unsigned u = __float_as_uint(f);
  return (unsigned short)((u + 0x7fffu + ((u >> 16) & 1u)) >> 16);  // RNE
}
static __device__ __forceinline__ float bf2f(unsigned short h) {
  return __uint_as_float(((unsigned)h) << 16);
}

// ---------------------------------------------------------------------------
// k_fused:
//   bid < 625 : edge-binning. Per edge: 1 atomicExch (head LL push, random),
//               1 coalesced 8B store next2[e]={old_head, src}, 1 atomicAdd
//               cnt_src (random). 2 random transactions/edge (was 3) and no
//               scattered 2B stores (was 41 MB of 64B-line writes).
//   bid >= 625: GEMM tile, hb = bf16(x@W) unscaled. Only x staged in LDS
//               (16 KB); W rows broadcast-read via L1/L2 (64 KB total, hot).
//               GEMM VALU work hides under the atomic wall.
// ---------------------------------------------------------------------------
__global__ __launch_bounds__(256) void k_fused(
    const float* __restrict__ x, const float* __restrict__ W,
    const int* __restrict__ src, const int* __restrict__ dst,
    int* __restrict__ cnt_src, unsigned int* __restrict__ head,
    uint2* __restrict__ next2, unsigned short* __restrict__ hb) {
  __shared__ float xl[32 * 128];  // 16 KB
  const int bid = blockIdx.x;
  const int tid = threadIdx.x;

  if (bid < CNT_BLOCKS) {
    // ---- binning role: 4 consecutive edges per thread ----
    const int e0 = (bid * 256 + tid) * 4;
    const int4 s4 = *(const int4*)(src + e0);
    const int4 d4 = *(const int4*)(dst + e0);
    // 4 independent rank/push atomics in flight
    unsigned r0 = atomicExch(&head[d4.x], (unsigned)(e0 + 0));
    unsigned r1 = atomicExch(&head[d4.y], (unsigned)(e0 + 1));
    unsigned r2 = atomicExch(&head[d4.z], (unsigned)(e0 + 2));
    unsigned r3 = atomicExch(&head[d4.w], (unsigned)(e0 + 3));
    // fire-and-forget degree counts
    atomicAdd(&cnt_src[s4.x], 1);
    atomicAdd(&cnt_src[s4.y], 1);
    atomicAdd(&cnt_src[s4.z], 1);
    atomicAdd(&cnt_src[s4.w], 1);
    // coalesced 32B/thread list-node stores
    next2[e0 + 0] = make_uint2(r0, (unsigned)s4.x);
    next2[e0 + 1] = make_uint2(r1, (unsigned)s4.y);
    next2[e0 + 2] = make_uint2(r2, (unsigned)s4.z);
    next2[e0 + 3] = make_uint2(r3, (unsigned)s4.w);
    return;
  }

  // ---- GEMM role: 32 nodes per block ----
  const int n0 = (bid - CNT_BLOCKS) * 32;
  const int td = tid & 31;  // d-group: d = td*4 .. td*4+3
  const int tn = tid >> 5;  // nodes tn*4 .. tn*4+3

  {
    const float4* xg = (const float4*)(x + (size_t)n0 * D);
    float4* xl4 = (float4*)xl;
#pragma unroll
    for (int j = 0; j < 4; ++j) xl4[tid + j * 256] = xg[tid + j * 256];
  }
  __syncthreads();

  float acc[4][4];
#pragma unroll
  for (int a = 0; a < 4; ++a)
#pragma unroll
    for (int q = 0; q < 4; ++q) acc[a][q] = 0.0f;

  const float4* W4 = (const float4*)W;
#pragma unroll 8
  for (int k = 0; k < 128; ++k) {
    float4 wv = W4[k * 32 + td];  // broadcast across tn groups; L1-hot
#pragma unroll
    for (int a = 0; a < 4; ++a) {
      float xa = xl[(tn * 4 + a) * D + k];
      acc[a][0] += xa * wv.x;
      acc[a][1] += xa * wv.y;
      acc[a][2] += xa * wv.z;
      acc[a][3] += xa * wv.w;
    }
  }

#pragma unroll
  for (int a = 0; a < 4; ++a) {
    const int n = n0 + tn * 4 + a;
    ushort4 v;
    v.x = f2bf(acc[a][0]);
    v.y = f2bf(acc[a][1]);
    v.z = f2bf(acc[a][2]);
    v.w = f2bf(acc[a][3]);
    ((ushort4*)(hb + (size_t)n * D))[td] = v;
  }
}

// ---------------------------------------------------------------------------
// k_gather: out[n] = b + sum over LL chain of dinv(s)*hb[s].
// 32 lanes per node (lane owns 4 dims), 8 nodes per block.
// Software-pipelined chase: next hop's {next,src} load issued before this
// hop's accumulation.
// ---------------------------------------------------------------------------
__global__ __launch_bounds__(256) void k_gather(
    const unsigned int* __restrict__ head, const int* __restrict__ cnt_src,
    const uint2* __restrict__ next2, const unsigned short* __restrict__ hb,
    const float* __restrict__ b, float* __restrict__ out) {
  const int tid = threadIdx.x;
  const int node = blockIdx.x * 8 + (tid >> 5);
  const int lane = tid & 31;

  float4 acc = {0.f, 0.f, 0.f, 0.f};

  unsigned e = head[node];
  uint2 pk = {ENDV, 0u};
  if (e != ENDV) pk = next2[e];
  while (e != ENDV) {
    const unsigned en = pk.x;
    const unsigned s = pk.y;
    uint2 pk_next = pk;
    if (en != ENDV) pk_next = next2[en];  // prefetch next hop (critical path)
    const float f = 1.0f / (float)cnt_src[s];  // s has >=1 out-edge
    ushort4 u = ((const ushort4*)(hb + (size_t)s * D))[lane];
    acc.x += f * bf2f(u.x);
    acc.y += f * bf2f(u.y);
    acc.z += f * bf2f(u.z);
    acc.w += f * bf2f(u.w);
    e = en;
    pk = pk_next;
  }

  const float4 bias = ((const float4*)b)[lane];
  float4 v;
  v.x = bias.x + acc.x;
  v.y = bias.y + acc.y;
  v.z = bias.z + acc.z;
  v.w = bias.w + acc.w;
  ((float4*)(out + (size_t)node * D))[lane] = v;
}

extern "C" void kernel_launch(void* const* d_in, const int* in_sizes, int n_in,
                              void* d_out, int out_size, void* d_ws, size_t ws_size,
                              hipStream_t stream) {
  const float* x = (const float*)d_in[0];
  const float* W = (const float*)d_in[1];
  const float* b = (const float*)d_in[2];
  const int* ei = (const int*)d_in[3];
  const int* src = ei;            // edge_index[0]
  const int* dst = ei + N_EDGES;  // edge_index[1]
  float* out = (float*)d_out;

  char* ws = (char*)d_ws;
  int* cnt_src = (int*)(ws + 0);                         // 160,000 B
  unsigned int* head = (unsigned int*)(ws + 160000);     // 160,000 B
  uint2* next2 = (uint2*)(ws + 320000);                  // 5,120,000 B
  unsigned short* hb = (unsigned short*)(ws + 5440000);  // 10,240,000 B (15.7 MB total)

  hipMemsetAsync(cnt_src, 0, 160000, stream);   // zero out-degree counters
  hipMemsetAsync(head, 0xFF, 160000, stream);   // head = ENDV sentinels
  k_fused<<<CNT_BLOCKS + GEMM_BLOCKS, 256, 0, stream>>>(x, W, src, dst, cnt_src,
                                                        head, next2, hb);
  k_gather<<<5000, 256, 0, stream>>>(head, cnt_src, next2, hb, b, out);
}